// Round 1
// baseline (15085.440 us; speedup 1.0000x reference)
//
#include <hip/hip_runtime.h>

// BotUpSaliency: 16-step recurrent V1 saliency model.
// State x,y: (2,512,512,12) f32. Per step: two 15x15x12x12 convs (W inhib, J excit)
// over gx=clip(x-1,0,1) with symmetric padding, 5x5 zero-padded box filter of
// sum_k gx for i_norm, per-pixel 12x12 psi matmul on gy, Euler updates.
// Output: max_k( (sum_t gx_t)/16 )  -> (2,512,512) f32.

#define HH 512
#define WW 512
#define BB 2
#define KK 12
#define TILE 16
#define HALO 7
#define TDIM 30   // TILE + 2*HALO

constexpr float EPS_C = 0.01f;
constexpr float G1_C  = 0.21f;
constexpr float G2_C  = 2.5f;
constexpr float LY_C  = 1.2f;
constexpr float J0_C  = 0.8f;

__device__ __forceinline__ float gxf(float x) { return fminf(fmaxf(x - 1.0f, 0.0f), 1.0f); }
__device__ __forceinline__ float gyf(float y) {
  float yc = fmaxf(y, 0.0f);
  return (yc <= LY_C) ? G1_C * yc : fmaf(G2_C, yc - LY_C, G1_C * LY_C);
}

__global__ void init_kernel(float* __restrict__ x, float* __restrict__ y,
                            float* __restrict__ oa, size_t n) {
  size_t i = (size_t)blockIdx.x * blockDim.x + threadIdx.x;
  if (i < n) { x[i] = 0.01f; y[i] = 1.0f; oa[i] = 0.0f; }
}

// Packed weights: pk[tap][c][0..11] = J[tap][c][k] (excit), pk[tap][c][12..23] = W[tap][c][k] (inhib)
__global__ void pack_kernel(const float* __restrict__ Wt, const float* __restrict__ Jt,
                            float* __restrict__ pk) {
  int idx = blockIdx.x * blockDim.x + threadIdx.x;
  if (idx >= 225 * 12 * 24) return;
  int k = idx % 24;
  int c = (idx / 24) % 12;
  int t = idx / (24 * 12);
  pk[idx] = (k < 12) ? Jt[(t * 12 + c) * 12 + k] : Wt[(t * 12 + c) * 12 + (k - 12)];
}

__launch_bounds__(256, 2)
__global__ void step_kernel(const float* __restrict__ xin, float* __restrict__ xout,
                            float* __restrict__ yb, float* __restrict__ oa,
                            const float* __restrict__ inp, const float* __restrict__ pk,
                            const float* __restrict__ psi) {
  __shared__ float tile[TDIM * TDIM * KK];   // gx, symmetric-padded   (43.2 KB)
  __shared__ float stile[20 * 20];           // channel-sums, zero-padded at image border
  __shared__ float psis[KK * KK];

  const int tx = threadIdx.x, ty = threadIdx.y;
  const int tid = ty * 16 + tx;
  const int b  = blockIdx.z;
  const int h0 = blockIdx.y * TILE, w0 = blockIdx.x * TILE;

  if (tid < KK * KK) psis[tid] = psi[tid];

  // ---- load gx tile (symmetric mirror at image borders) ----
  for (int p = tid; p < TDIM * TDIM; p += 256) {
    int r = p / TDIM, cp = p % TDIM;
    int gh = h0 + r - HALO, gw = w0 + cp - HALO;
    gh = gh < 0 ? -gh - 1 : (gh >= HH ? 2 * HH - 1 - gh : gh);
    gw = gw < 0 ? -gw - 1 : (gw >= WW ? 2 * WW - 1 - gw : gw);
    const float4* src = (const float4*)(xin + (((size_t)b * HH + gh) * WW + gw) * KK);
    float4* dst = (float4*)(tile + p * KK);
    #pragma unroll
    for (int q = 0; q < 3; ++q) {
      float4 v = src[q];
      v.x = gxf(v.x); v.y = gxf(v.y); v.z = gxf(v.z); v.w = gxf(v.w);
      dst[q] = v;
    }
  }
  __syncthreads();

  // ---- channel-sum subtile for box filter (ZERO outside image, per SAME conv) ----
  for (int p = tid; p < 400; p += 256) {
    int r = p / 20, cp = p % 20;
    int gh = h0 + r - 2, gw = w0 + cp - 2;
    float sv = 0.0f;
    if (gh >= 0 && gh < HH && gw >= 0 && gw < WW) {
      const float* t = tile + ((r + 5) * TDIM + (cp + 5)) * KK;
      #pragma unroll
      for (int c = 0; c < KK; ++c) sv += t[c];
    }
    stile[p] = sv;
  }
  __syncthreads();

  // ---- fused W+J convolution: 225 taps x 12 in x 24 out ----
  float accJ[12], accW[12];
  #pragma unroll
  for (int k = 0; k < 12; ++k) { accJ[k] = 0.0f; accW[k] = 0.0f; }

  const float* __restrict__ pkp = pk;
  #pragma unroll 1
  for (int i = 0; i < 15; ++i) {
    const float* trow = tile + ((ty + i) * TDIM + tx) * KK;
    #pragma unroll 1
    for (int j = 0; j < 15; ++j) {
      const float* src = trow + j * KK;
      #pragma unroll
      for (int c4 = 0; c4 < 3; ++c4) {
        float4 g = ((const float4*)src)[c4];
        float ge[4] = {g.x, g.y, g.z, g.w};
        #pragma unroll
        for (int e = 0; e < 4; ++e) {
          float v = ge[e];
          const float* wr = pkp + (c4 * 4 + e) * 24;   // uniform address -> s_load
          #pragma unroll
          for (int k = 0; k < 12; ++k) accJ[k] = fmaf(wr[k], v, accJ[k]);
          #pragma unroll
          for (int k = 0; k < 12; ++k) accW[k] = fmaf(wr[12 + k], v, accW[k]);
        }
      }
      pkp += 288;
    }
  }

  // ---- i_norm from 5x5 box of channel sums ----
  float box = 0.0f;
  #pragma unroll
  for (int u = 0; u < 5; ++u)
    #pragma unroll
    for (int v = 0; v < 5; ++v)
      box += stile[(ty + u) * 20 + (tx + v)];
  float bn = box * (1.0f / 25.0f);
  float i_norm = 0.85f - 2.0f * bn * bn;

  // ---- pointwise epilogue ----
  const size_t base = (((size_t)b * HH + (h0 + ty)) * WW + (w0 + tx)) * KK;
  float xv[12], yv[12], gyv[12], inv[12];
  #pragma unroll
  for (int q = 0; q < 3; ++q) {
    float4 v = ((const float4*)(xin + base))[q];
    xv[q*4+0]=v.x; xv[q*4+1]=v.y; xv[q*4+2]=v.z; xv[q*4+3]=v.w;
    float4 u = ((const float4*)(yb + base))[q];
    yv[q*4+0]=u.x; yv[q*4+1]=u.y; yv[q*4+2]=u.z; yv[q*4+3]=u.w;
    float4 w = ((const float4*)(inp + base))[q];
    inv[q*4+0]=w.x; inv[q*4+1]=w.y; inv[q*4+2]=w.z; inv[q*4+3]=w.w;
  }
  #pragma unroll
  for (int k = 0; k < 12; ++k) gyv[k] = gyf(yv[k]);

  const float* ctr = tile + ((ty + HALO) * TDIM + (tx + HALO)) * KK;

  float xn[12], yn[12], gn[12];
  #pragma unroll
  for (int k = 0; k < 12; ++k) {
    float gxk = ctr[k];
    float psit = 0.0f;
    #pragma unroll
    for (int c = 0; c < 12; ++c) psit = fmaf(gyv[c], psis[c * 12 + k], psit);
    float ynew = yv[k] + EPS_C * (-yv[k] + gxk + accW[k] + 1.0f);
    float xnew = xv[k] + EPS_C * (J0_C * gxk + accJ[k] + inv[k] + i_norm
                                  - xv[k] - gyv[k] - psit);
    xn[k] = xnew;
    yn[k] = ynew;
    gn[k] = gxf(xnew);
  }

  #pragma unroll
  for (int q = 0; q < 3; ++q) {
    float4 v; v.x=xn[q*4+0]; v.y=xn[q*4+1]; v.z=xn[q*4+2]; v.w=xn[q*4+3];
    ((float4*)(xout + base))[q] = v;
    float4 u; u.x=yn[q*4+0]; u.y=yn[q*4+1]; u.z=yn[q*4+2]; u.w=yn[q*4+3];
    ((float4*)(yb + base))[q] = u;
    float4 o = ((const float4*)(oa + base))[q];
    o.x += gn[q*4+0]; o.y += gn[q*4+1]; o.z += gn[q*4+2]; o.w += gn[q*4+3];
    ((float4*)(oa + base))[q] = o;
  }
}

__global__ void final_kernel(const float* __restrict__ oa, float* __restrict__ out, size_t n) {
  size_t p = (size_t)blockIdx.x * blockDim.x + threadIdx.x;
  if (p >= n) return;
  const float* o = oa + p * KK;
  float m = o[0];
  #pragma unroll
  for (int c = 1; c < KK; ++c) m = fmaxf(m, o[c]);
  out[p] = m * (1.0f / 16.0f);
}

extern "C" void kernel_launch(void* const* d_in, const int* in_sizes, int n_in,
                              void* d_out, int out_size, void* d_ws, size_t ws_size,
                              hipStream_t stream) {
  const float* inp = (const float*)d_in[0];   // (2,512,512,12)
  const float* Wt  = (const float*)d_in[1];   // (15,15,12,12)
  const float* Jt  = (const float*)d_in[2];   // (15,15,12,12)
  const float* psi = (const float*)d_in[3];   // (1,1,12,12)

  float* ws = (float*)d_ws;
  const size_t N = (size_t)BB * HH * WW * KK;     // 6,291,456 floats
  float* xA = ws;
  float* xB = ws + N;
  float* yb = ws + 2 * N;
  float* oa = ws + 3 * N;
  float* pk = ws + 4 * N;                          // 64,800 floats
  // total ws use: (4N + 64800) * 4 B ~= 101 MB

  init_kernel<<<dim3((unsigned)((N + 255) / 256)), dim3(256), 0, stream>>>(xA, yb, oa, N);
  pack_kernel<<<dim3((225 * 12 * 24 + 255) / 256), dim3(256), 0, stream>>>(Wt, Jt, pk);

  dim3 grid(WW / TILE, HH / TILE, BB);
  dim3 blk(16, 16);
  const float* xi = xA;
  float* xo = xB;
  for (int s = 0; s < 16; ++s) {
    step_kernel<<<grid, blk, 0, stream>>>(xi, xo, yb, oa, inp, pk, psi);
    const float* t = xo; xo = (float*)xi; xi = t;
  }

  final_kernel<<<dim3((unsigned)(((size_t)BB * HH * WW + 255) / 256)), dim3(256), 0, stream>>>(
      oa, (float*)d_out, (size_t)BB * HH * WW);
}

// Round 2
// 12084.245 us; speedup vs baseline: 1.2484x; 1.2484x over previous
//
#include <hip/hip_runtime.h>

// BotUpSaliency: 16-step recurrent V1 saliency model — SPARSE weight version.
// W/J (15x15x12x12) are mostly exact zeros by construction (association field).
// Build per-output-k compact lists of (lds_offset, weight) once on device
// (deterministic ballot compaction), then each step's conv iterates only the
// nonzero entries with uniform (scalar) weight access.

#define HH 512
#define WW 512
#define BB 2
#define KK 12
#define TILE 16
#define HALO 7
#define TDIM 30            // TILE + 2*HALO
#define ROWS (TDIM * KK + 1)   // 361 floats: +1 pad so lane banks spread 2-way (free)
#define LSTRIDE 2700       // max entries per output k (15*15*12)

constexpr float EPS_C = 0.01f;
constexpr float G1_C  = 0.21f;
constexpr float G2_C  = 2.5f;
constexpr float LY_C  = 1.2f;
constexpr float J0_C  = 0.8f;

__device__ __forceinline__ float gxf(float x) { return fminf(fmaxf(x - 1.0f, 0.0f), 1.0f); }
__device__ __forceinline__ float gyf(float y) {
  float yc = fmaxf(y, 0.0f);
  return (yc <= LY_C) ? G1_C * yc : fmaf(G2_C, yc - LY_C, G1_C * LY_C);
}

__global__ void init_kernel(float* __restrict__ x, float* __restrict__ y,
                            float* __restrict__ oa, size_t n) {
  size_t i = (size_t)blockIdx.x * blockDim.x + threadIdx.x;
  if (i < n) { x[i] = 0.01f; y[i] = 1.0f; oa[i] = 0.0f; }
}

// One wave per output k (blocks 0..11 -> J, 12..23 -> W). Deterministic
// ballot compaction preserving (i,j,c) ascending order.
__global__ void build_lists(const float* __restrict__ Wt, const float* __restrict__ Jt,
                            uint2* __restrict__ lists, int* __restrict__ cnt) {
  const int k = blockIdx.x;                 // 0..23
  const float* src = (k < 12) ? Jt : Wt;    // HWIO: [i][j][c][k]
  const int ko = k % 12;
  const int lane = threadIdx.x;             // 64 threads = 1 wave
  int base = 0;
  for (int t0 = 0; t0 < 2700; t0 += 64) {
    int t = t0 + lane;                      // t = (i*15 + j)*12 + c
    float w = 0.0f;
    if (t < 2700) w = src[t * 12 + ko];
    bool nz = (w != 0.0f);
    unsigned long long m = __ballot(nz);
    int pre = __popcll(m & ((1ull << lane) - 1ull));
    if (nz) {
      int i = t / 180, j = (t / 12) % 15, c = t % 12;
      lists[k * LSTRIDE + base + pre] =
          make_uint2((unsigned)(i * ROWS + j * KK + c), __float_as_uint(w));
    }
    base += __popcll(m);
  }
  if (lane == 0) cnt[k] = base;
}

__launch_bounds__(256, 2)
__global__ void step_kernel(const float* __restrict__ xin, float* __restrict__ xout,
                            float* __restrict__ yb, float* __restrict__ oa,
                            const float* __restrict__ inp,
                            const uint2* __restrict__ lists, const int* __restrict__ cnt,
                            const float* __restrict__ psi) {
  __shared__ float tile[TDIM * ROWS];   // gx, symmetric-padded, padded rows (43.3 KB)
  __shared__ float stile[20 * 20];      // channel-sums, zero outside image
  __shared__ float psis[KK * KK];

  const int tx = threadIdx.x, ty = threadIdx.y;
  const int tid = ty * 16 + tx;
  const int b  = blockIdx.z;
  const int h0 = blockIdx.y * TILE, w0 = blockIdx.x * TILE;

  if (tid < KK * KK) psis[tid] = psi[tid];

  // ---- load gx tile (symmetric mirror at image borders) ----
  for (int p = tid; p < TDIM * TDIM; p += 256) {
    int r = p / TDIM, cp = p % TDIM;
    int gh = h0 + r - HALO, gw = w0 + cp - HALO;
    gh = gh < 0 ? -gh - 1 : (gh >= HH ? 2 * HH - 1 - gh : gh);
    gw = gw < 0 ? -gw - 1 : (gw >= WW ? 2 * WW - 1 - gw : gw);
    const float4* src = (const float4*)(xin + (((size_t)b * HH + gh) * WW + gw) * KK);
    float* dst = tile + r * ROWS + cp * KK;
    #pragma unroll
    for (int q = 0; q < 3; ++q) {
      float4 v = src[q];
      dst[q * 4 + 0] = gxf(v.x); dst[q * 4 + 1] = gxf(v.y);
      dst[q * 4 + 2] = gxf(v.z); dst[q * 4 + 3] = gxf(v.w);
    }
  }
  __syncthreads();

  // ---- channel-sum subtile for box filter (ZERO outside image, SAME conv) ----
  for (int p = tid; p < 400; p += 256) {
    int r = p / 20, cp = p % 20;
    int gh = h0 + r - 2, gw = w0 + cp - 2;
    float sv = 0.0f;
    if (gh >= 0 && gh < HH && gw >= 0 && gw < WW) {
      const float* t = tile + (r + 5) * ROWS + (cp + 5) * KK;
      #pragma unroll
      for (int c = 0; c < KK; ++c) sv += t[c];
    }
    stile[p] = sv;
  }
  __syncthreads();

  // ---- sparse W+J convolution: per-output-k nonzero lists ----
  const float* __restrict__ tbase = tile + ty * ROWS + tx * KK;
  float accJ[12], accW[12];

  #pragma unroll
  for (int kk = 0; kk < 12; ++kk) {
    const uint2* __restrict__ lst = lists + kk * LSTRIDE;
    const int n = cnt[kk];
    float a0 = 0.0f, a1 = 0.0f;
    int e = 0;
    for (; e + 8 <= n; e += 8) {
      uint2 q0 = lst[e+0], q1 = lst[e+1], q2 = lst[e+2], q3 = lst[e+3];
      uint2 q4 = lst[e+4], q5 = lst[e+5], q6 = lst[e+6], q7 = lst[e+7];
      float g0 = tbase[q0.x], g1 = tbase[q1.x], g2 = tbase[q2.x], g3 = tbase[q3.x];
      float g4 = tbase[q4.x], g5 = tbase[q5.x], g6 = tbase[q6.x], g7 = tbase[q7.x];
      a0 = fmaf(__uint_as_float(q0.y), g0, a0); a1 = fmaf(__uint_as_float(q1.y), g1, a1);
      a0 = fmaf(__uint_as_float(q2.y), g2, a0); a1 = fmaf(__uint_as_float(q3.y), g3, a1);
      a0 = fmaf(__uint_as_float(q4.y), g4, a0); a1 = fmaf(__uint_as_float(q5.y), g5, a1);
      a0 = fmaf(__uint_as_float(q6.y), g6, a0); a1 = fmaf(__uint_as_float(q7.y), g7, a1);
    }
    for (; e < n; ++e) {
      uint2 q = lst[e];
      a0 = fmaf(__uint_as_float(q.y), tbase[q.x], a0);
    }
    accJ[kk] = a0 + a1;
  }

  #pragma unroll
  for (int kk = 0; kk < 12; ++kk) {
    const uint2* __restrict__ lst = lists + (12 + kk) * LSTRIDE;
    const int n = cnt[12 + kk];
    float a0 = 0.0f, a1 = 0.0f;
    int e = 0;
    for (; e + 8 <= n; e += 8) {
      uint2 q0 = lst[e+0], q1 = lst[e+1], q2 = lst[e+2], q3 = lst[e+3];
      uint2 q4 = lst[e+4], q5 = lst[e+5], q6 = lst[e+6], q7 = lst[e+7];
      float g0 = tbase[q0.x], g1 = tbase[q1.x], g2 = tbase[q2.x], g3 = tbase[q3.x];
      float g4 = tbase[q4.x], g5 = tbase[q5.x], g6 = tbase[q6.x], g7 = tbase[q7.x];
      a0 = fmaf(__uint_as_float(q0.y), g0, a0); a1 = fmaf(__uint_as_float(q1.y), g1, a1);
      a0 = fmaf(__uint_as_float(q2.y), g2, a0); a1 = fmaf(__uint_as_float(q3.y), g3, a1);
      a0 = fmaf(__uint_as_float(q4.y), g4, a0); a1 = fmaf(__uint_as_float(q5.y), g5, a1);
      a0 = fmaf(__uint_as_float(q6.y), g6, a0); a1 = fmaf(__uint_as_float(q7.y), g7, a1);
    }
    for (; e < n; ++e) {
      uint2 q = lst[e];
      a0 = fmaf(__uint_as_float(q.y), tbase[q.x], a0);
    }
    accW[kk] = a0 + a1;
  }

  // ---- i_norm from 5x5 box of channel sums ----
  float box = 0.0f;
  #pragma unroll
  for (int u = 0; u < 5; ++u)
    #pragma unroll
    for (int v = 0; v < 5; ++v)
      box += stile[(ty + u) * 20 + (tx + v)];
  float bn = box * (1.0f / 25.0f);
  float i_norm = 0.85f - 2.0f * bn * bn;

  // ---- pointwise epilogue ----
  const size_t base = (((size_t)b * HH + (h0 + ty)) * WW + (w0 + tx)) * KK;
  float xv[12], yv[12], gyv[12], inv[12];
  #pragma unroll
  for (int q = 0; q < 3; ++q) {
    float4 v = ((const float4*)(xin + base))[q];
    xv[q*4+0]=v.x; xv[q*4+1]=v.y; xv[q*4+2]=v.z; xv[q*4+3]=v.w;
    float4 u = ((const float4*)(yb + base))[q];
    yv[q*4+0]=u.x; yv[q*4+1]=u.y; yv[q*4+2]=u.z; yv[q*4+3]=u.w;
    float4 w = ((const float4*)(inp + base))[q];
    inv[q*4+0]=w.x; inv[q*4+1]=w.y; inv[q*4+2]=w.z; inv[q*4+3]=w.w;
  }
  #pragma unroll
  for (int k = 0; k < 12; ++k) gyv[k] = gyf(yv[k]);

  const float* ctr = tile + (ty + HALO) * ROWS + (tx + HALO) * KK;

  float xn[12], yn[12], gn[12];
  #pragma unroll
  for (int k = 0; k < 12; ++k) {
    float gxk = ctr[k];
    float psit = 0.0f;
    #pragma unroll
    for (int c = 0; c < 12; ++c) psit = fmaf(gyv[c], psis[c * 12 + k], psit);
    float ynew = yv[k] + EPS_C * (-yv[k] + gxk + accW[k] + 1.0f);
    float xnew = xv[k] + EPS_C * (J0_C * gxk + accJ[k] + inv[k] + i_norm
                                  - xv[k] - gyv[k] - psit);
    xn[k] = xnew;
    yn[k] = ynew;
    gn[k] = gxf(xnew);
  }

  #pragma unroll
  for (int q = 0; q < 3; ++q) {
    float4 v; v.x=xn[q*4+0]; v.y=xn[q*4+1]; v.z=xn[q*4+2]; v.w=xn[q*4+3];
    ((float4*)(xout + base))[q] = v;
    float4 u; u.x=yn[q*4+0]; u.y=yn[q*4+1]; u.z=yn[q*4+2]; u.w=yn[q*4+3];
    ((float4*)(yb + base))[q] = u;
    float4 o = ((const float4*)(oa + base))[q];
    o.x += gn[q*4+0]; o.y += gn[q*4+1]; o.z += gn[q*4+2]; o.w += gn[q*4+3];
    ((float4*)(oa + base))[q] = o;
  }
}

__global__ void final_kernel(const float* __restrict__ oa, float* __restrict__ out, size_t n) {
  size_t p = (size_t)blockIdx.x * blockDim.x + threadIdx.x;
  if (p >= n) return;
  const float* o = oa + p * KK;
  float m = o[0];
  #pragma unroll
  for (int c = 1; c < KK; ++c) m = fmaxf(m, o[c]);
  out[p] = m * (1.0f / 16.0f);
}

extern "C" void kernel_launch(void* const* d_in, const int* in_sizes, int n_in,
                              void* d_out, int out_size, void* d_ws, size_t ws_size,
                              hipStream_t stream) {
  const float* inp = (const float*)d_in[0];   // (2,512,512,12)
  const float* Wt  = (const float*)d_in[1];   // (15,15,12,12) HWIO
  const float* Jt  = (const float*)d_in[2];   // (15,15,12,12) HWIO
  const float* psi = (const float*)d_in[3];   // (1,1,12,12)

  float* ws = (float*)d_ws;
  const size_t N = (size_t)BB * HH * WW * KK;     // 6,291,456 floats
  float* xA = ws;
  float* xB = ws + N;
  float* yb = ws + 2 * N;
  float* oa = ws + 3 * N;
  uint2* lists = (uint2*)(ws + 4 * N);            // 24*2700 uint2 = 518.4 KB
  int*   cnt   = (int*)(lists + 24 * LSTRIDE);    // 24 ints
  // total ws use ~ 101.2 MB

  build_lists<<<dim3(24), dim3(64), 0, stream>>>(Wt, Jt, lists, cnt);
  init_kernel<<<dim3((unsigned)((N + 255) / 256)), dim3(256), 0, stream>>>(xA, yb, oa, N);

  dim3 grid(WW / TILE, HH / TILE, BB);
  dim3 blk(16, 16);
  const float* xi = xA;
  float* xo = xB;
  for (int s = 0; s < 16; ++s) {
    step_kernel<<<grid, blk, 0, stream>>>(xi, xo, yb, oa, inp, lists, cnt, psi);
    const float* t = xo; xo = (float*)xi; xi = t;
  }

  final_kernel<<<dim3((unsigned)(((size_t)BB * HH * WW + 255) / 256)), dim3(256), 0, stream>>>(
      oa, (float*)d_out, (size_t)BB * HH * WW);
}

// Round 3
// 3794.457 us; speedup vs baseline: 3.9757x; 3.1847x over previous
//
#include <hip/hip_runtime.h>

// BotUpSaliency: 16-step recurrent V1 saliency model — MFMA (split-bf16) version.
// Conv as implicit GEMM: S[px, k'] = sum_{tap,c} g[px+tap, c] * w[tap,c,k'],
// done in bf16 MFMA (16x16x32) with 3-pass hi/lo error compensation:
//   S ≈ Ah*Bh + Al*Bh + Ah*Bl   (drops only Al*Bl ~ 2^-18 rel)
// K=32 packs 2 taps x 16 chans (12 real + 4 pad; pad rows of B are zero).
// Per block: 32x32 output tile, 46x46 halo gx tile staged in LDS as bf16 hi/lo.

#define HH 512
#define WW 512
#define KK 12
#define TILE 32
#define TW 46              // halo tile dim (TILE + 14)
#define SSTR 25            // S row stride in f32 (24 + 1 pad)

typedef __attribute__((ext_vector_type(8))) short short8v;
typedef __attribute__((ext_vector_type(4))) float float4v;

constexpr float EPS_C = 0.01f;
constexpr float G1_C  = 0.21f;
constexpr float G2_C  = 2.5f;
constexpr float LY_C  = 1.2f;
constexpr float J0_C  = 0.8f;

__device__ __forceinline__ float gxf(float x) { return fminf(fmaxf(x - 1.0f, 0.0f), 1.0f); }
__device__ __forceinline__ float gyf(float y) {
  float yc = fmaxf(y, 0.0f);
  return (yc <= LY_C) ? G1_C * yc : fmaf(G2_C, yc - LY_C, G1_C * LY_C);
}
__device__ __forceinline__ unsigned short f2bf(float f) {
  unsigned u = __float_as_uint(f);
  return (unsigned short)((u + 0x7FFFu + ((u >> 16) & 1u)) >> 16);
}
__device__ __forceinline__ float bf2f(unsigned short h) {
  return __uint_as_float(((unsigned)h) << 16);
}

__global__ void init_kernel(float* __restrict__ x, float* __restrict__ y,
                            float* __restrict__ oa, size_t n) {
  size_t i = (size_t)blockIdx.x * blockDim.x + threadIdx.x;
  if (i < n) { x[i] = 0.01f; y[i] = 1.0f; oa[i] = 0.0f; }
}

// B fragments pre-packed in exact MFMA lane order.
// frag = (di*8 + djp)*4 + f, f in {0:J_hi, 1:W_hi, 2:J_lo, 3:W_lo}.
// K-slot kk = (lane>>4)*8 + j: tap half = kk>>4 (0: dj=2*djp, 1: dj=2*djp+1),
// chan = kk&15 (>=12 -> 0). n = lane&15 (>=12 -> 0).
__global__ void pack_kernel(const float* __restrict__ Wt, const float* __restrict__ Jt,
                            short* __restrict__ Bpk) {
  int frag = blockIdx.x;          // 480
  int l = threadIdx.x;            // 64
  int di  = frag >> 5;
  int djp = (frag >> 2) & 7;
  int f   = frag & 3;
  int n = l & 15, sel = l >> 4;
  short8v out;
  #pragma unroll
  for (int j = 0; j < 8; ++j) {
    int kk = sel * 8 + j;
    int tb = kk >> 4;             // 0 = tapA, 1 = tapB
    int ch = kk & 15;
    int dj = 2 * djp + tb;
    float w = 0.0f;
    if (ch < 12 && n < 12 && dj < 15) {
      const float* s = (f & 1) ? Wt : Jt;      // HWIO [di][dj][ch][n]
      w = s[((di * 15 + dj) * 12 + ch) * 12 + n];
    }
    unsigned short hi = f2bf(w);
    out[j] = (f < 2) ? (short)hi : (short)f2bf(w - bf2f(hi));
  }
  ((short8v*)Bpk)[frag * 64 + l] = out;
}

__launch_bounds__(1024)
__global__ void step_kernel(const float* __restrict__ xin, float* __restrict__ xout,
                            float* __restrict__ yb, float* __restrict__ oa,
                            const float* __restrict__ inp, const short* __restrict__ Bpk,
                            const float* __restrict__ psi) {
  // region A: gx tiles (hi | lo), later aliased by S[1024][25] f32
  __shared__ char smemA[2 * TW * TW * 32];     // 135,424 B
  __shared__ float stile[36 * 36];
  __shared__ float psis[144];
  short* tile_hi = (short*)smemA;
  short* tile_lo = (short*)(smemA + TW * TW * 32);
  float* S = (float*)smemA;

  const int tid = threadIdx.x;
  const int b = blockIdx.z;
  const int h0 = blockIdx.y * TILE, w0 = blockIdx.x * TILE;

  if (tid < 144) psis[tid] = psi[tid];

  // ---- stage gx halo -> bf16 hi/lo records (16 chans, 32B, swizzled halves) ----
  for (int p = tid; p < TW * TW; p += 1024) {
    int r = p / TW, c = p % TW;
    int ghr = h0 - 7 + r, gwr = w0 - 7 + c;
    int gh = ghr < 0 ? -ghr - 1 : (ghr >= HH ? 2 * HH - 1 - ghr : ghr);
    int gw = gwr < 0 ? -gwr - 1 : (gwr >= WW ? 2 * WW - 1 - gwr : gwr);
    const float4* src = (const float4*)(xin + (((size_t)b * HH + gh) * WW + gw) * KK);
    float g[12]; float cs = 0.0f;
    #pragma unroll
    for (int q = 0; q < 3; ++q) {
      float4 v = src[q];
      g[q*4+0] = gxf(v.x); g[q*4+1] = gxf(v.y); g[q*4+2] = gxf(v.z); g[q*4+3] = gxf(v.w);
      cs += g[q*4+0] + g[q*4+1] + g[q*4+2] + g[q*4+3];
    }
    short8v h0v, h1v, l0v, l1v;
    #pragma unroll
    for (int k = 0; k < 8; ++k) {
      unsigned short hb = f2bf(g[k]);
      h0v[k] = (short)hb;
      l0v[k] = (short)f2bf(g[k] - bf2f(hb));
    }
    #pragma unroll
    for (int k = 0; k < 4; ++k) {
      unsigned short hb = f2bf(g[8 + k]);
      h1v[k] = (short)hb;
      l1v[k] = (short)f2bf(g[8 + k] - bf2f(hb));
    }
    #pragma unroll
    for (int k = 4; k < 8; ++k) { h1v[k] = 0; l1v[k] = 0; }
    int swz = (p >> 2) & 1;
    short8v* Hb = (short8v*)tile_hi + p * 2;
    short8v* Lb = (short8v*)tile_lo + p * 2;
    Hb[swz] = h0v; Hb[1 - swz] = h1v;
    Lb[swz] = l0v; Lb[1 - swz] = l1v;
    if (r >= 5 && r < 41 && c >= 5 && c < 41) {
      bool inimg = (ghr >= 0 && ghr < HH && gwr >= 0 && gwr < WW);
      stile[(r - 5) * 36 + (c - 5)] = inimg ? cs : 0.0f;
    }
  }
  __syncthreads();

  // ---- MFMA conv: 15(di) x 8(djp) K-steps, K=32 = 2 taps x 16 chans ----
  const int wave = tid >> 6, lane = tid & 63;
  const int rb  = (wave >> 1) * 4;        // wave's 4 pixel rows
  const int wl0 = (wave & 1) * 16;        // wave's 16-pixel col segment
  const int m16 = lane & 15, sel = lane >> 4;
  const int selh = sel >> 1;              // 0 = tapA, 1 = tapB
  const int selb = (sel & 1) << 4;        // byte offset of chan-half
  const int pcb = wl0 + m16;

  float4v acc[4][2];
  #pragma unroll
  for (int mt = 0; mt < 4; ++mt) {
    acc[mt][0] = (float4v){0.f, 0.f, 0.f, 0.f};
    acc[mt][1] = (float4v){0.f, 0.f, 0.f, 0.f};
  }

  #pragma unroll 1
  for (int di = 0; di < 15; ++di) {
    #pragma unroll 1
    for (int djp = 0; djp < 8; ++djp) {
      const short8v* bf = (const short8v*)Bpk + (size_t)((di * 8 + djp) * 4) * 64 + lane;
      short8v B0 = bf[0], B1 = bf[64], B2 = bf[128], B3 = bf[192];
      int dj = 2 * djp + selh; dj = dj > 14 ? 14 : dj;   // pad tap dup (B=0 there)
      int Pbase = (rb + di) * TW + pcb + dj;
      #pragma unroll
      for (int mt = 0; mt < 4; ++mt) {
        int P = Pbase + mt * TW;
        int ba = ((P << 5) | selb) ^ ((P & 4) << 2);     // half-swap swizzle
        short8v Ah = *(const short8v*)((const char*)tile_hi + ba);
        short8v Al = *(const short8v*)((const char*)tile_lo + ba);
        acc[mt][0] = __builtin_amdgcn_mfma_f32_16x16x32_bf16(Ah, B0, acc[mt][0], 0, 0, 0);
        acc[mt][1] = __builtin_amdgcn_mfma_f32_16x16x32_bf16(Ah, B1, acc[mt][1], 0, 0, 0);
        acc[mt][0] = __builtin_amdgcn_mfma_f32_16x16x32_bf16(Al, B0, acc[mt][0], 0, 0, 0);
        acc[mt][1] = __builtin_amdgcn_mfma_f32_16x16x32_bf16(Al, B1, acc[mt][1], 0, 0, 0);
        acc[mt][0] = __builtin_amdgcn_mfma_f32_16x16x32_bf16(Ah, B2, acc[mt][0], 0, 0, 0);
        acc[mt][1] = __builtin_amdgcn_mfma_f32_16x16x32_bf16(Ah, B3, acc[mt][1], 0, 0, 0);
      }
    }
  }
  __syncthreads();   // all tile reads done; free region A for S

  // ---- scatter acc -> S[px][25] (f32), C layout: M = (lane>>4)*4+reg, N = lane&15 ----
  if (m16 < 12) {
    #pragma unroll
    for (int mt = 0; mt < 4; ++mt) {
      #pragma unroll
      for (int nt = 0; nt < 2; ++nt) {
        #pragma unroll
        for (int rg = 0; rg < 4; ++rg) {
          int px = ((rb + mt) * TILE) + wl0 + sel * 4 + rg;
          S[px * SSTR + nt * 12 + m16] = acc[mt][nt][rg];
        }
      }
    }
  }
  __syncthreads();

  // ---- pointwise epilogue: one thread per pixel ----
  {
    int r = tid >> 5, c = tid & 31;
    float box = 0.0f;
    #pragma unroll
    for (int u = 0; u < 5; ++u)
      #pragma unroll
      for (int v = 0; v < 5; ++v)
        box += stile[(r + u) * 36 + (c + v)];
    float bn = box * (1.0f / 25.0f);
    float i_norm = 0.85f - 2.0f * bn * bn;

    const size_t base = (((size_t)b * HH + (h0 + r)) * WW + (w0 + c)) * KK;
    float xv[12], yv[12], gyv[12], inv[12];
    #pragma unroll
    for (int q = 0; q < 3; ++q) {
      float4 v = ((const float4*)(xin + base))[q];
      xv[q*4+0]=v.x; xv[q*4+1]=v.y; xv[q*4+2]=v.z; xv[q*4+3]=v.w;
      float4 u = ((const float4*)(yb + base))[q];
      yv[q*4+0]=u.x; yv[q*4+1]=u.y; yv[q*4+2]=u.z; yv[q*4+3]=u.w;
      float4 w = ((const float4*)(inp + base))[q];
      inv[q*4+0]=w.x; inv[q*4+1]=w.y; inv[q*4+2]=w.z; inv[q*4+3]=w.w;
    }
    #pragma unroll
    for (int k = 0; k < 12; ++k) gyv[k] = gyf(yv[k]);

    const float* Sp = S + (size_t)tid * SSTR;
    float xn[12], yn[12], gn[12];
    #pragma unroll
    for (int k = 0; k < 12; ++k) {
      float gxk = gxf(xv[k]);           // exact f32 gx (recomputed)
      float psit = 0.0f;
      #pragma unroll
      for (int cc = 0; cc < 12; ++cc) psit = fmaf(gyv[cc], psis[cc * 12 + k], psit);
      float accJ = Sp[k];
      float accW = Sp[12 + k];
      float ynew = yv[k] + EPS_C * (-yv[k] + gxk + accW + 1.0f);
      float xnew = xv[k] + EPS_C * (J0_C * gxk + accJ + inv[k] + i_norm
                                    - xv[k] - gyv[k] - psit);
      xn[k] = xnew; yn[k] = ynew; gn[k] = gxf(xnew);
    }

    #pragma unroll
    for (int q = 0; q < 3; ++q) {
      float4 v; v.x=xn[q*4+0]; v.y=xn[q*4+1]; v.z=xn[q*4+2]; v.w=xn[q*4+3];
      ((float4*)(xout + base))[q] = v;
      float4 u; u.x=yn[q*4+0]; u.y=yn[q*4+1]; u.z=yn[q*4+2]; u.w=yn[q*4+3];
      ((float4*)(yb + base))[q] = u;
      float4 o = ((const float4*)(oa + base))[q];
      o.x += gn[q*4+0]; o.y += gn[q*4+1]; o.z += gn[q*4+2]; o.w += gn[q*4+3];
      ((float4*)(oa + base))[q] = o;
    }
  }
}

__global__ void final_kernel(const float* __restrict__ oa, float* __restrict__ out, size_t n) {
  size_t p = (size_t)blockIdx.x * blockDim.x + threadIdx.x;
  if (p >= n) return;
  const float* o = oa + p * KK;
  float m = o[0];
  #pragma unroll
  for (int c = 1; c < KK; ++c) m = fmaxf(m, o[c]);
  out[p] = m * (1.0f / 16.0f);
}

extern "C" void kernel_launch(void* const* d_in, const int* in_sizes, int n_in,
                              void* d_out, int out_size, void* d_ws, size_t ws_size,
                              hipStream_t stream) {
  const float* inp = (const float*)d_in[0];   // (2,512,512,12)
  const float* Wt  = (const float*)d_in[1];   // (15,15,12,12) HWIO
  const float* Jt  = (const float*)d_in[2];   // (15,15,12,12) HWIO
  const float* psi = (const float*)d_in[3];   // (1,1,12,12)

  float* ws = (float*)d_ws;
  const size_t N = (size_t)2 * HH * WW * KK;      // 6,291,456 floats
  float* xA = ws;
  float* xB = ws + N;
  float* yb = ws + 2 * N;
  float* oa = ws + 3 * N;
  short* Bpk = (short*)(ws + 4 * N);              // 480 frags * 512 shorts = 480 KB

  pack_kernel<<<dim3(480), dim3(64), 0, stream>>>(Wt, Jt, Bpk);
  init_kernel<<<dim3((unsigned)((N + 255) / 256)), dim3(256), 0, stream>>>(xA, yb, oa, N);

  dim3 grid(WW / TILE, HH / TILE, 2);
  const float* xi = xA;
  float* xo = xB;
  for (int s = 0; s < 16; ++s) {
    step_kernel<<<grid, dim3(1024), 0, stream>>>(xi, xo, yb, oa, inp, Bpk, psi);
    const float* t = xo; xo = (float*)xi; xi = t;
  }

  final_kernel<<<dim3((unsigned)(((size_t)2 * HH * WW + 255) / 256)), dim3(256), 0, stream>>>(
      oa, (float*)d_out, (size_t)2 * HH * WW);
}

// Round 4
// 312.556 us; speedup vs baseline: 48.2648x; 12.1401x over previous
//
#include <hip/hip_runtime.h>

// BotUpSaliency: 16-step recurrent V1 saliency model — activity-gated version.
// Key structural fact: gx = clip(x-1,0,1) is a rectified signal; the two 15x15
// convolutions and the i_norm box filter consume ONLY gx. We maintain a per-
// 16x16-tile activity flag (any gx>0). A tile whose 3x3 tile-neighborhood
// (covers the 7-pixel conv halo and 2-pixel box halo) is inactive has
// conv == 0 and i_norm == 0.85 exactly, so only the pointwise Euler update
// runs. A faithful dense fallback (direct conv with symmetric padding) handles
// active tiles for general inputs. Additional monotone gates: y stays bitwise
// unchanged until a tile's y-dirty bit sets (skip y read/write), and the
// out-accumulator RMW is skipped while the tile's new gx is all zero.

#define HH 512
#define WW 512
#define KK 12
#define TS 16            // tile side
#define NT 32            // tiles per image side
#define NFLAG (2 * NT * NT)   // flags per buffer (b, ty, tx)

constexpr float EPS_C = 0.01f;
constexpr float G1_C  = 0.21f;
constexpr float G2_C  = 2.5f;
constexpr float LY_C  = 1.2f;
constexpr float J0_C  = 0.8f;

__device__ __forceinline__ float gxf(float x) { return fminf(fmaxf(x - 1.0f, 0.0f), 1.0f); }
__device__ __forceinline__ float gyf(float y) {
  float yc = fmaxf(y, 0.0f);
  return (yc <= LY_C) ? G1_C * yc : fmaf(G2_C, yc - LY_C, G1_C * LY_C);
}
__device__ __forceinline__ int refl(int i, int n) {
  return i < 0 ? -i - 1 : (i >= n ? 2 * n - 1 - i : i);
}

__global__ void init_kernel(float* __restrict__ oa, int* __restrict__ flags, size_t n) {
  size_t i = (size_t)blockIdx.x * blockDim.x + threadIdx.x;
  if (i < n) oa[i] = 0.0f;
  if (i < 2 * NFLAG) flags[i] = 0;
}

// flags bit0: tile has any gx>0 (spatial neighbors care)
// flags bit1: tile's y differs from init value 1.0 somewhere (monotone)
__launch_bounds__(256)
__global__ void step_kernel(const float* __restrict__ xin, float* __restrict__ xout,
                            float* __restrict__ yb, float* __restrict__ oa,
                            const float* __restrict__ inp,
                            const float* __restrict__ Wt, const float* __restrict__ Jt,
                            const float* __restrict__ psi,
                            const int* __restrict__ fin, int* __restrict__ fout,
                            int first) {
  __shared__ float psis[KK * KK];
  __shared__ int nb[9];
  __shared__ int wor[4];

  const int tid = threadIdx.x;
  const int b = blockIdx.z;
  const int tyb = blockIdx.y, txb = blockIdx.x;

  if (tid < KK * KK) psis[tid] = psi[tid];
  if (tid < 9) {
    int dy = tid / 3 - 1, dx = tid % 3 - 1;
    int ty = min(max(tyb + dy, 0), NT - 1);
    int tx = min(max(txb + dx, 0), NT - 1);
    nb[tid] = fin[(b * NT + ty) * NT + tx];
  }
  __syncthreads();

  const int own = nb[4];
  const int dense = (nb[0] | nb[1] | nb[2] | nb[3] | nb[4] | nb[5] | nb[6] | nb[7] | nb[8]) & 1;

  const int r = tid >> 4, c = tid & 15;
  const int gh = tyb * TS + r, gw = txb * TS + c;
  const size_t base = (((size_t)b * HH + gh) * WW + gw) * KK;

  // ---- conv terms (cold general path; skipped when neighborhood inactive) ----
  float accJ[KK], accW[KK];
  #pragma unroll
  for (int k = 0; k < KK; ++k) { accJ[k] = 0.0f; accW[k] = 0.0f; }
  float i_norm = 0.85f;

  if (dense) {
    #pragma unroll 1
    for (int di = 0; di < 15; ++di) {
      int ih = refl(gh - 7 + di, HH);
      #pragma unroll 1
      for (int dj = 0; dj < 15; ++dj) {
        int iw = refl(gw - 7 + dj, WW);
        const float* p = xin + (((size_t)b * HH + ih) * WW + iw) * KK;
        const float* wj = Jt + (size_t)(di * 15 + dj) * KK * KK;
        const float* wi = Wt + (size_t)(di * 15 + dj) * KK * KK;
        #pragma unroll 1
        for (int cc = 0; cc < KK; ++cc) {
          float g = gxf(p[cc]);
          if (g > 0.0f) {
            #pragma unroll
            for (int k = 0; k < KK; ++k) {
              accJ[k] = fmaf(g, wj[cc * KK + k], accJ[k]);
              accW[k] = fmaf(g, wi[cc * KK + k], accW[k]);
            }
          }
        }
      }
    }
    float box = 0.0f;
    #pragma unroll 1
    for (int u = 0; u < 5; ++u) {
      int ih = gh - 2 + u;
      if (ih < 0 || ih >= HH) continue;
      #pragma unroll 1
      for (int v = 0; v < 5; ++v) {
        int iw = gw - 2 + v;
        if (iw < 0 || iw >= WW) continue;
        const float* p = xin + (((size_t)b * HH + ih) * WW + iw) * KK;
        float s = 0.0f;
        #pragma unroll
        for (int cc = 0; cc < KK; ++cc) s += gxf(p[cc]);
        box += s;
      }
    }
    float bn = box * (1.0f / 25.0f);
    i_norm = 0.85f - 2.0f * bn * bn;
  }

  // ---- pointwise state update ----
  float xv[KK], yv[KK], inv[KK];
  if (first) {
    #pragma unroll
    for (int k = 0; k < KK; ++k) { xv[k] = 0.01f; yv[k] = 1.0f; }
  } else {
    #pragma unroll
    for (int q = 0; q < 3; ++q) {
      float4 v = ((const float4*)(xin + base))[q];
      xv[q*4+0]=v.x; xv[q*4+1]=v.y; xv[q*4+2]=v.z; xv[q*4+3]=v.w;
    }
    if (own & 2) {
      #pragma unroll
      for (int q = 0; q < 3; ++q) {
        float4 u = ((const float4*)(yb + base))[q];
        yv[q*4+0]=u.x; yv[q*4+1]=u.y; yv[q*4+2]=u.z; yv[q*4+3]=u.w;
      }
    } else {
      #pragma unroll
      for (int k = 0; k < KK; ++k) yv[k] = 1.0f;   // bitwise-unchanged since init
    }
  }
  #pragma unroll
  for (int q = 0; q < 3; ++q) {
    float4 w = ((const float4*)(inp + base))[q];
    inv[q*4+0]=w.x; inv[q*4+1]=w.y; inv[q*4+2]=w.z; inv[q*4+3]=w.w;
  }

  float gyv[KK];
  #pragma unroll
  for (int k = 0; k < KK; ++k) gyv[k] = gyf(yv[k]);

  float xn[KK], yn[KK], gn[KK];
  bool anyg = false, ych = false;
  #pragma unroll
  for (int k = 0; k < KK; ++k) {
    float gxk = gxf(xv[k]);
    float psit = 0.0f;
    #pragma unroll
    for (int cc = 0; cc < KK; ++cc) psit = fmaf(gyv[cc], psis[cc * KK + k], psit);
    float ynew = yv[k] + EPS_C * (-yv[k] + gxk + accW[k] + 1.0f);
    float xnew = xv[k] + EPS_C * (J0_C * gxk + accJ[k] + inv[k] + i_norm
                                  - xv[k] - gyv[k] - psit);
    xn[k] = xnew;
    yn[k] = ynew;
    gn[k] = gxf(xnew);
    anyg = anyg || (gn[k] > 0.0f);
    ych  = ych  || (__float_as_uint(ynew) != __float_as_uint(yv[k]));
  }

  #pragma unroll
  for (int q = 0; q < 3; ++q) {
    float4 v; v.x=xn[q*4+0]; v.y=xn[q*4+1]; v.z=xn[q*4+2]; v.w=xn[q*4+3];
    ((float4*)(xout + base))[q] = v;
  }

  // ---- block-wide reduce of gates ----
  int wf = (__any(anyg) ? 1 : 0) | (__any(ych) ? 2 : 0);
  if ((tid & 63) == 0) wor[tid >> 6] = wf;
  __syncthreads();
  const int orf = wor[0] | wor[1] | wor[2] | wor[3];

  if (first || (orf & 2)) {      // materialize y (always on first step)
    #pragma unroll
    for (int q = 0; q < 3; ++q) {
      float4 u; u.x=yn[q*4+0]; u.y=yn[q*4+1]; u.z=yn[q*4+2]; u.w=yn[q*4+3];
      ((float4*)(yb + base))[q] = u;
    }
  }
  if (orf & 1) {                 // accumulate out only when some gx_new > 0
    #pragma unroll
    for (int q = 0; q < 3; ++q) {
      float4 o = ((const float4*)(oa + base))[q];
      o.x += gn[q*4+0]; o.y += gn[q*4+1]; o.z += gn[q*4+2]; o.w += gn[q*4+3];
      ((float4*)(oa + base))[q] = o;
    }
  }
  if (tid == 0) {
    int ydirty = ((own & 2) | (orf & 2)) ? 2 : 0;
    fout[(b * NT + tyb) * NT + txb] = (orf & 1) | ydirty;
  }
}

__global__ void final_kernel(const float* __restrict__ oa, float* __restrict__ out, size_t n) {
  size_t p = (size_t)blockIdx.x * blockDim.x + threadIdx.x;
  if (p >= n) return;
  const float* o = oa + p * KK;
  float m = o[0];
  #pragma unroll
  for (int c = 1; c < KK; ++c) m = fmaxf(m, o[c]);
  out[p] = m * (1.0f / 16.0f);
}

extern "C" void kernel_launch(void* const* d_in, const int* in_sizes, int n_in,
                              void* d_out, int out_size, void* d_ws, size_t ws_size,
                              hipStream_t stream) {
  const float* inp = (const float*)d_in[0];   // (2,512,512,12)
  const float* Wt  = (const float*)d_in[1];   // (15,15,12,12) HWIO
  const float* Jt  = (const float*)d_in[2];   // (15,15,12,12) HWIO
  const float* psi = (const float*)d_in[3];   // (1,1,12,12)

  float* ws = (float*)d_ws;
  const size_t N = (size_t)2 * HH * WW * KK;      // 6,291,456 floats
  float* xA = ws;
  float* xB = ws + N;
  float* yb = ws + 2 * N;
  float* oa = ws + 3 * N;
  int* flags = (int*)(ws + 4 * N);                // 2 buffers x 2048 ints

  init_kernel<<<dim3((unsigned)((N + 255) / 256)), dim3(256), 0, stream>>>(oa, flags, N);

  dim3 grid(NT, NT, 2);
  const float* xi = xA;
  float* xo = xB;
  for (int s = 0; s < 16; ++s) {
    const int* fi = flags + (s & 1) * NFLAG;
    int* fo = flags + ((s + 1) & 1) * NFLAG;
    step_kernel<<<grid, dim3(256), 0, stream>>>(xi, xo, yb, oa, inp, Wt, Jt, psi,
                                                fi, fo, s == 0 ? 1 : 0);
    const float* t = xo; xo = (float*)xi; xi = t;
  }

  final_kernel<<<dim3((unsigned)(((size_t)2 * HH * WW + 255) / 256)), dim3(256), 0, stream>>>(
      oa, (float*)d_out, (size_t)2 * HH * WW);
}

// Round 5
// 62.422 us; speedup vs baseline: 241.6683x; 5.0071x over previous
//
#include <hip/hip_runtime.h>
#include <hip/hip_cooperative_groups.h>

namespace cg = cooperative_groups;

// BotUpSaliency — single cooperative-kernel version.
// While gx = clip(x-1,0,1) is identically zero (true for any input bounded
// well below the firing threshold; verified per-pixel at runtime), the
// 16-step recurrence is per-pixel decoupled:
//   y stays bitwise 1.0, gy = 0.21, i_norm = 0.85, psit_k = 0.21*colsum(psi)_k
//   x <- x + 0.01*(inp_k + c_k - x),  c_k = 0.85 - 0.21 - 0.21*colsum_k
// which is monotone toward inp+c_k, so max over the trajectory is iterate 16.
// Phase 1 runs this in registers (local fire detection, threshold 0.99 with
// ~0.84 margin), one grid.sync, and if nothing fired anywhere the output is
// exactly zero. The faithful tile-gated 16-step fallback (round-4 logic) runs
// inside the same kernel only when the fire flag is set.

#define HH 512
#define WW 512
#define KK 12
#define NT 32
#define NTILE 2048      // 2 * 32 * 32 tiles
#define NBLK 512
#define NTHR 256
#define TPB 4           // tiles / pixel-groups per block

constexpr float EPS_C = 0.01f;
constexpr float G1_C  = 0.21f;
constexpr float G2_C  = 2.5f;
constexpr float LY_C  = 1.2f;
constexpr float J0_C  = 0.8f;

__device__ __forceinline__ float gxf(float x) { return fminf(fmaxf(x - 1.0f, 0.0f), 1.0f); }
__device__ __forceinline__ float gyf(float y) {
  float yc = fmaxf(y, 0.0f);
  return (yc <= LY_C) ? G1_C * yc : fmaf(G2_C, yc - LY_C, G1_C * LY_C);
}
__device__ __forceinline__ int refl(int i, int n) {
  return i < 0 ? -i - 1 : (i >= n ? 2 * n - 1 - i : i);
}

__global__ void zero_gf(int* __restrict__ gf) { if (threadIdx.x == 0) *gf = 0; }

__launch_bounds__(NTHR, 2)
__global__ void fused_kernel(const float* __restrict__ inp, const float* __restrict__ Wt,
                             const float* __restrict__ Jt, const float* __restrict__ psi,
                             float* __restrict__ xA, float* __restrict__ xB,
                             float* __restrict__ yb, float* __restrict__ oa,
                             int* __restrict__ flags, int* __restrict__ gf,
                             float* __restrict__ out) {
  cg::grid_group grid = cg::this_grid();
  const int tid = threadIdx.x;
  const int bid = blockIdx.x;

  __shared__ int sflag;
  __shared__ float psis[KK * KK];
  __shared__ int nb[9];
  __shared__ int wor[4];

  // ---- decoupled-regime per-channel constant from the actual psi input ----
  float ck[KK];
  #pragma unroll
  for (int k = 0; k < KK; ++k) {
    float s = 0.0f;
    #pragma unroll
    for (int c = 0; c < KK; ++c) s += psi[c * KK + k];
    ck[k] = 0.85f - 0.21f - 0.21f * s;
  }

  // ---- phase 1: local decoupled trajectory, fire detection ----
  bool fired = false;
  #pragma unroll 1
  for (int pp = 0; pp < TPB; ++pp) {
    size_t px = ((size_t)bid * TPB + pp) * NTHR + tid;
    const float4* ip = (const float4*)(inp + px * KK);
    float4 i0 = ip[0], i1 = ip[1], i2 = ip[2];
    float iv[KK] = {i0.x, i0.y, i0.z, i0.w, i1.x, i1.y, i1.z, i1.w,
                    i2.x, i2.y, i2.z, i2.w};
    float xr[KK];
    #pragma unroll
    for (int k = 0; k < KK; ++k) xr[k] = 0.01f;
    #pragma unroll 1
    for (int s = 0; s < 16; ++s) {
      #pragma unroll
      for (int k = 0; k < KK; ++k) xr[k] = fmaf(EPS_C, iv[k] + ck[k] - xr[k], xr[k]);
    }
    #pragma unroll
    for (int k = 0; k < KK; ++k)
      fired = fired || (xr[k] > 0.99f) || !(xr[k] == xr[k]);   // NaN-safe
  }

  if (tid == 0) sflag = 0;
  __syncthreads();
  if (fired) sflag = 1;            // benign race, same value
  __syncthreads();
  if (tid == 0 && sflag) atomicOr(gf, 1);
  grid.sync();
  if (tid == 0) sflag = atomicOr(gf, 0);   // coherent device-scope read
  __syncthreads();

  if (!sflag) {
    // Nothing ever fires -> gx_t == 0 for all t -> out is exactly zero.
    #pragma unroll
    for (int pp = 0; pp < TPB; ++pp) {
      size_t px = ((size_t)bid * TPB + pp) * NTHR + tid;
      out[px] = 0.0f;
    }
    return;                         // uniform across the whole grid
  }

  // ================= faithful fallback (tile-gated, 16 steps) =================
  if (tid < KK * KK) psis[tid] = psi[tid];

  // init state for owned tiles
  #pragma unroll 1
  for (int pp = 0; pp < TPB; ++pp) {
    int tile = bid * TPB + pp;
    int b = tile >> 10, rem = tile & 1023;
    int tyb = rem >> 5, txb = rem & 31;
    int r = tid >> 4, c = tid & 15;
    size_t base = (((size_t)b * HH + tyb * 16 + r) * WW + txb * 16 + c) * KK;
    #pragma unroll
    for (int q = 0; q < 3; ++q) {
      ((float4*)(xA + base))[q] = make_float4(0.01f, 0.01f, 0.01f, 0.01f);
      ((float4*)(yb + base))[q] = make_float4(1.0f, 1.0f, 1.0f, 1.0f);
      ((float4*)(oa + base))[q] = make_float4(0.0f, 0.0f, 0.0f, 0.0f);
    }
    if (tid == 0) flags[tile] = 0;   // buffer 0, step 0: nothing active
  }
  grid.sync();

  #pragma unroll 1
  for (int s = 0; s < 16; ++s) {
    const float* xin = (s & 1) ? xB : xA;
    float* xout = (s & 1) ? xA : xB;
    const int* fin = flags + (s & 1) * NTILE;
    int* fout = flags + ((s + 1) & 1) * NTILE;

    #pragma unroll 1
    for (int pp = 0; pp < TPB; ++pp) {
      int tile = bid * TPB + pp;
      int b = tile >> 10, rem = tile & 1023;
      int tyb = rem >> 5, txb = rem & 31;

      __syncthreads();
      if (tid < 9) {
        int dy = tid / 3 - 1, dx = tid % 3 - 1;
        int ty = min(max(tyb + dy, 0), NT - 1);
        int tx = min(max(txb + dx, 0), NT - 1);
        nb[tid] = fin[(b * NT + ty) * NT + tx];
      }
      __syncthreads();
      const int dense =
          (nb[0] | nb[1] | nb[2] | nb[3] | nb[4] | nb[5] | nb[6] | nb[7] | nb[8]) & 1;

      const int r = tid >> 4, c = tid & 15;
      const int gh = tyb * 16 + r, gw = txb * 16 + c;
      const size_t base = (((size_t)b * HH + gh) * WW + gw) * KK;

      float accJ[KK], accW[KK];
      #pragma unroll
      for (int k = 0; k < KK; ++k) { accJ[k] = 0.0f; accW[k] = 0.0f; }
      float i_norm = 0.85f;

      if (dense) {
        #pragma unroll 1
        for (int di = 0; di < 15; ++di) {
          int ih = refl(gh - 7 + di, HH);
          #pragma unroll 1
          for (int dj = 0; dj < 15; ++dj) {
            int iw = refl(gw - 7 + dj, WW);
            const float* p = xin + (((size_t)b * HH + ih) * WW + iw) * KK;
            const float* wj = Jt + (size_t)(di * 15 + dj) * KK * KK;
            const float* wi = Wt + (size_t)(di * 15 + dj) * KK * KK;
            #pragma unroll 1
            for (int cc = 0; cc < KK; ++cc) {
              float g = gxf(p[cc]);
              if (g > 0.0f) {
                #pragma unroll
                for (int k = 0; k < KK; ++k) {
                  accJ[k] = fmaf(g, wj[cc * KK + k], accJ[k]);
                  accW[k] = fmaf(g, wi[cc * KK + k], accW[k]);
                }
              }
            }
          }
        }
        float box = 0.0f;
        #pragma unroll 1
        for (int u = 0; u < 5; ++u) {
          int ih = gh - 2 + u;
          if (ih < 0 || ih >= HH) continue;
          #pragma unroll 1
          for (int v = 0; v < 5; ++v) {
            int iw = gw - 2 + v;
            if (iw < 0 || iw >= WW) continue;
            const float* p = xin + (((size_t)b * HH + ih) * WW + iw) * KK;
            float sv = 0.0f;
            #pragma unroll
            for (int cc = 0; cc < KK; ++cc) sv += gxf(p[cc]);
            box += sv;
          }
        }
        float bn = box * (1.0f / 25.0f);
        i_norm = 0.85f - 2.0f * bn * bn;
      }

      float xv[KK], yv[KK], inv[KK];
      #pragma unroll
      for (int q = 0; q < 3; ++q) {
        float4 v = ((const float4*)(xin + base))[q];
        xv[q*4+0]=v.x; xv[q*4+1]=v.y; xv[q*4+2]=v.z; xv[q*4+3]=v.w;
        float4 u = ((const float4*)(yb + base))[q];
        yv[q*4+0]=u.x; yv[q*4+1]=u.y; yv[q*4+2]=u.z; yv[q*4+3]=u.w;
        float4 w = ((const float4*)(inp + base))[q];
        inv[q*4+0]=w.x; inv[q*4+1]=w.y; inv[q*4+2]=w.z; inv[q*4+3]=w.w;
      }
      float gyv[KK];
      #pragma unroll
      for (int k = 0; k < KK; ++k) gyv[k] = gyf(yv[k]);

      float xn[KK], yn[KK], gn[KK];
      bool anyg = false;
      #pragma unroll
      for (int k = 0; k < KK; ++k) {
        float gxk = gxf(xv[k]);
        float psit = 0.0f;
        #pragma unroll
        for (int cc = 0; cc < KK; ++cc) psit = fmaf(gyv[cc], psis[cc * KK + k], psit);
        float ynew = yv[k] + EPS_C * (-yv[k] + gxk + accW[k] + 1.0f);
        float xnew = xv[k] + EPS_C * (J0_C * gxk + accJ[k] + inv[k] + i_norm
                                      - xv[k] - gyv[k] - psit);
        xn[k] = xnew; yn[k] = ynew; gn[k] = gxf(xnew);
        anyg = anyg || (gn[k] > 0.0f);
      }

      #pragma unroll
      for (int q = 0; q < 3; ++q) {
        float4 v; v.x=xn[q*4+0]; v.y=xn[q*4+1]; v.z=xn[q*4+2]; v.w=xn[q*4+3];
        ((float4*)(xout + base))[q] = v;
        float4 u; u.x=yn[q*4+0]; u.y=yn[q*4+1]; u.z=yn[q*4+2]; u.w=yn[q*4+3];
        ((float4*)(yb + base))[q] = u;
        float4 o = ((const float4*)(oa + base))[q];
        o.x += gn[q*4+0]; o.y += gn[q*4+1]; o.z += gn[q*4+2]; o.w += gn[q*4+3];
        ((float4*)(oa + base))[q] = o;
      }

      int wf = __any(anyg) ? 1 : 0;
      if ((tid & 63) == 0) wor[tid >> 6] = wf;
      __syncthreads();
      if (tid == 0) fout[tile] = wor[0] | wor[1] | wor[2] | wor[3];
    }
    grid.sync();
  }

  // final: out = max_k (oa / 16)
  #pragma unroll 1
  for (int pp = 0; pp < TPB; ++pp) {
    int tile = bid * TPB + pp;
    int b = tile >> 10, rem = tile & 1023;
    int tyb = rem >> 5, txb = rem & 31;
    int r = tid >> 4, c = tid & 15;
    int gh = tyb * 16 + r, gw = txb * 16 + c;
    const float* o = oa + (((size_t)b * HH + gh) * WW + gw) * KK;
    float m = o[0];
    #pragma unroll
    for (int cc = 1; cc < KK; ++cc) m = fmaxf(m, o[cc]);
    out[((size_t)b * HH + gh) * WW + gw] = m * (1.0f / 16.0f);
  }
}

extern "C" void kernel_launch(void* const* d_in, const int* in_sizes, int n_in,
                              void* d_out, int out_size, void* d_ws, size_t ws_size,
                              hipStream_t stream) {
  const float* inp = (const float*)d_in[0];   // (2,512,512,12)
  const float* Wt  = (const float*)d_in[1];   // (15,15,12,12) HWIO
  const float* Jt  = (const float*)d_in[2];   // (15,15,12,12) HWIO
  const float* psi = (const float*)d_in[3];   // (1,1,12,12)

  float* ws = (float*)d_ws;
  const size_t N = (size_t)2 * HH * WW * KK;      // 6,291,456 floats
  float* xA = ws;
  float* xB = ws + N;
  float* yb = ws + 2 * N;
  float* oa = ws + 3 * N;
  int* flags = (int*)(ws + 4 * N);                // 2 * 2048 ints
  int* gf = flags + 2 * NTILE;
  float* out = (float*)d_out;

  zero_gf<<<dim3(1), dim3(64), 0, stream>>>(gf);

  void* args[] = {(void*)&inp, (void*)&Wt, (void*)&Jt, (void*)&psi,
                  (void*)&xA, (void*)&xB, (void*)&yb, (void*)&oa,
                  (void*)&flags, (void*)&gf, (void*)&out};
  hipLaunchCooperativeKernel((void*)fused_kernel, dim3(NBLK), dim3(NTHR),
                             args, 0, stream);
}